// Round 3
// baseline (954.483 us; speedup 1.0000x reference)
//
#include <hip/hip_runtime.h>
#include <stdint.h>

typedef unsigned short ushort_t;
typedef __attribute__((ext_vector_type(8))) short bf8_t;     // 8 x bf16 (4 VGPRs)
typedef __attribute__((ext_vector_type(4))) float f4_t;      // MFMA accumulator
typedef __attribute__((ext_vector_type(4))) unsigned short us4_t;

#define TT 128

__device__ __forceinline__ ushort_t f2bf(float f) {
  uint32_t u = __builtin_bit_cast(uint32_t, f);
  u += 0x7fffu + ((u >> 16) & 1u);
  return (ushort_t)(u >> 16);
}
__device__ __forceinline__ float bf2f(ushort_t h) {
  uint32_t u = ((uint32_t)h) << 16;
  return __builtin_bit_cast(float, u);
}
__device__ __forceinline__ float sigm(float x) { return 1.f / (1.f + __expf(-x)); }
__device__ __forceinline__ float tanh_f(float x) {
  float a = fabsf(x);
  float e = __expf(-2.f * a);
  float t = (1.f - e) / (1.f + e);
  return x < 0.f ? -t : t;
}

// ---------- pack kernels ----------
// Gate-interleaved: physical output col n = col*4 + gate.  WT[n][k] = W_{g=n&3}[k][j=n>>2]
__global__ void k_pack_w(const float* W0, const float* W1, const float* W2, const float* W3,
                         ushort_t* __restrict__ o) {
  int idx = blockIdx.x * 256 + threadIdx.x;   // 0..262143
  int n = idx >> 8, k = idx & 255;
  int g = n & 3, j = n >> 2;
  const float* Wg = g == 0 ? W0 : g == 1 ? W1 : g == 2 ? W2 : W3;
  o[(size_t)n * 256 + k] = f2bf(Wg[k * 256 + j]);
}

// U fragment-pack for the k_scan stream, kt-outer order:
// frag index = ((w*8 + kt)*8 + grp)*64 + lane, grp = g*2 + ct2.
// elem e = U_g[kt*32 + (lane>>4)*8 + e][w*32 + ct2*16 + (lane&15)]
__global__ void k_pack_u(const float* U0, const float* U1, const float* U2, const float* U3,
                         ushort_t* __restrict__ o) {
  int idx = blockIdx.x * 256 + threadIdx.x;   // 0..32767
  int lane = idx & 63, grp = (idx >> 6) & 7, kt = (idx >> 9) & 7, w = idx >> 12;
  int g = grp >> 1, ct2 = grp & 1;
  const float* Ug = g == 0 ? U0 : g == 1 ? U1 : g == 2 ? U2 : U3;
  int kb = kt * 32 + (lane >> 4) * 8;
  int col = w * 32 + ct2 * 16 + (lane & 15);
#pragma unroll
  for (int e2 = 0; e2 < 8; ++e2)
    o[(size_t)idx * 8 + e2] = f2bf(Ug[(size_t)(kb + e2) * 256 + col]);
}

// bias2[n] (n = j*4+g) = bW_g[j] + bU_g[j]
__global__ void k_bias(const float* a0, const float* a1, const float* a2, const float* a3,
                       const float* b0, const float* b1, const float* b2, const float* b3,
                       float* __restrict__ o) {
  int n = blockIdx.x * 256 + threadIdx.x;  // 0..1023
  int g = n & 3, j = n >> 2;
  const float* pa = g == 0 ? a0 : g == 1 ? a1 : g == 2 ? a2 : a3;
  const float* pb = g == 0 ? b0 : g == 1 ? b1 : g == 2 ? b2 : b3;
  o[n] = pa[j] + pb[j];
}

// ---------- K1: P = emb @ W_all (emb f32 read + convert fused; bf16 MFMA) ----------
__global__ __launch_bounds__(256) void k1_gemm(const float* __restrict__ A,      // emb f32 [32000][256]
                                               const ushort_t* __restrict__ Bm,  // WT bf16 [1024][256]
                                               ushort_t* __restrict__ P) {       // [32000][1024]
  __shared__ ushort_t Al[128 * 32];
  __shared__ ushort_t Bl[128 * 32];
  const int tid = threadIdx.x;
  const int lane = tid & 63;
  const int w = tid >> 6;
  const int mt = blockIdx.x >> 3;
  const int nt = blockIdx.x & 7;
  const int m0 = mt * 128, n0 = nt * 128;
  const int qr = (w >> 1) * 64, qc = (w & 1) * 64;

  f4_t acc[4][4];
#pragma unroll
  for (int i = 0; i < 4; ++i)
#pragma unroll
    for (int j = 0; j < 4; ++j) acc[i][j] = f4_t{0.f, 0.f, 0.f, 0.f};

  const int r0 = tid >> 2, s0 = tid & 3;  // rows 0..63
  const int r1 = 64 + r0;                 // rows 64..127

  for (int k0 = 0; k0 < 256; k0 += 32) {
    float4 a00 = *(const float4*)(A + (size_t)(m0 + r0) * 256 + k0 + s0 * 8);
    float4 a01 = *(const float4*)(A + (size_t)(m0 + r0) * 256 + k0 + s0 * 8 + 4);
    float4 a10 = *(const float4*)(A + (size_t)(m0 + r1) * 256 + k0 + s0 * 8);
    float4 a11 = *(const float4*)(A + (size_t)(m0 + r1) * 256 + k0 + s0 * 8 + 4);
    bf8_t b0 = *(const bf8_t*)(Bm + (size_t)(n0 + r0) * 256 + k0 + s0 * 8);
    bf8_t b1 = *(const bf8_t*)(Bm + (size_t)(n0 + r1) * 256 + k0 + s0 * 8);
    bf8_t pa0, pa1;
    pa0[0] = (short)f2bf(a00.x); pa0[1] = (short)f2bf(a00.y);
    pa0[2] = (short)f2bf(a00.z); pa0[3] = (short)f2bf(a00.w);
    pa0[4] = (short)f2bf(a01.x); pa0[5] = (short)f2bf(a01.y);
    pa0[6] = (short)f2bf(a01.z); pa0[7] = (short)f2bf(a01.w);
    pa1[0] = (short)f2bf(a10.x); pa1[1] = (short)f2bf(a10.y);
    pa1[2] = (short)f2bf(a10.z); pa1[3] = (short)f2bf(a10.w);
    pa1[4] = (short)f2bf(a11.x); pa1[5] = (short)f2bf(a11.y);
    pa1[6] = (short)f2bf(a11.z); pa1[7] = (short)f2bf(a11.w);
    __syncthreads();
    *(bf8_t*)(Al + (size_t)tid * 8) = pa0;
    *(bf8_t*)(Al + (size_t)(256 + tid) * 8) = pa1;
    *(bf8_t*)(Bl + (size_t)tid * 8) = b0;
    *(bf8_t*)(Bl + (size_t)(256 + tid) * 8) = b1;
    __syncthreads();
    bf8_t af[4], bfr[4];
#pragma unroll
    for (int i = 0; i < 4; ++i) {
      af[i]  = *(const bf8_t*)(Al + (qr + i * 16 + (lane & 15)) * 32 + (lane >> 4) * 8);
      bfr[i] = *(const bf8_t*)(Bl + (qc + i * 16 + (lane & 15)) * 32 + (lane >> 4) * 8);
    }
#pragma unroll
    for (int i = 0; i < 4; ++i)
#pragma unroll
      for (int j = 0; j < 4; ++j)
        acc[i][j] = __builtin_amdgcn_mfma_f32_16x16x32_bf16(af[i], bfr[j], acc[i][j], 0, 0, 0);
  }
#pragma unroll
  for (int i = 0; i < 4; ++i)
#pragma unroll
    for (int j = 0; j < 4; ++j)
#pragma unroll
      for (int r = 0; r < 4; ++r) {
        int row = m0 + qr + i * 16 + (lane >> 4) * 4 + r;
        int col = n0 + qc + j * 16 + (lane & 15);
        P[(size_t)row * 1024 + col] = f2bf(acc[i][j][r]);
      }
}

// ---------- K2: block-local recurrent scan (no cross-block sync) ----------
// 32 blocks x 16 batch rows. 8 waves; wave w owns hidden cols [w*32, w*32+32)
// (2 x 16-col tiles) for all 4 gates. U (512KB bf16) streams from L2 every
// step as pre-packed MFMA B-fragments, double-buffered per kt. h exchanged
// through LDS (double-buffered, 1 barrier/step).
__global__ __launch_bounds__(512, 2) void k_scan(
    const ushort_t* __restrict__ P, const ushort_t* __restrict__ UP,
    const float* __restrict__ bias, const int* __restrict__ cap,
    float* __restrict__ hfin) {
  __shared__ ushort_t hl[2][16][264];   // +8 pad: bank-spread for stride-row reads
  const int b = blockIdx.x;
  const int tid = threadIdx.x, lane = tid & 63, w = tid >> 6;
  const int l15 = lane & 15, l16 = lane >> 4;
  const int jc0 = w * 32 + l15;        // ct2=0 column
  const int jc1 = jc0 + 16;            // ct2=1 column
  const int rowl = l16 * 4;            // this lane's C/D rows (local 0..15)

  const float4 bs0 = *(const float4*)(bias + jc0 * 4);
  const float4 bs1 = *(const float4*)(bias + jc1 * 4);

  // wave's U stream base: frag (kt,grp) at elem offset ((w*8+kt)*8+grp)*512
  const ushort_t* ubase = UP + (size_t)w * 64 * 512 + (size_t)lane * 8;

  f4_t c0 = {0.f, 0.f, 0.f, 0.f}, c1 = {0.f, 0.f, 0.f, 0.f};

  for (int t = 0; t < TT; ++t) {
    // issue this step's token + P gathers first; they hide under the U/MFMA phase
    int tok[4];
#pragma unroll
    for (int r = 0; r < 4; ++r) tok[r] = cap[(b * 16 + rowl + r) * TT + t];
    us4_t pf0[4], pf1[4];
#pragma unroll
    for (int r = 0; r < 4; ++r) {
      pf0[r] = *(const us4_t*)(P + (size_t)tok[r] * 1024 + jc0 * 4);
      pf1[r] = *(const us4_t*)(P + (size_t)tok[r] * 1024 + jc1 * 4);
    }

    f4_t acc[2][4];
#pragma unroll
    for (int i = 0; i < 2; ++i)
#pragma unroll
      for (int g = 0; g < 4; ++g) acc[i][g] = f4_t{0.f, 0.f, 0.f, 0.f};

    if (t > 0) {
      const ushort_t* hrow = &hl[(t + 1) & 1][0][0];   // h(t-1) buffer
      bf8_t ua[8], ub[8], af, afn;
#pragma unroll
      for (int g8 = 0; g8 < 8; ++g8) ua[g8] = *(const bf8_t*)(ubase + g8 * 512);
      af = *(const bf8_t*)(hrow + l15 * 264 + l16 * 8);

#define KT_STEP(CUR, NXT, KT)                                                        \
      if ((KT) < 7) {                                                                \
        _Pragma("unroll")                                                            \
        for (int g8 = 0; g8 < 8; ++g8)                                               \
          NXT[g8] = *(const bf8_t*)(ubase + (((KT) + 1) * 8 + g8) * 512);            \
        afn = *(const bf8_t*)(hrow + l15 * 264 + ((KT) + 1) * 32 + l16 * 8);         \
      }                                                                              \
      _Pragma("unroll")                                                              \
      for (int grp = 0; grp < 8; ++grp)                                              \
        acc[grp & 1][grp >> 1] =                                                     \
            __builtin_amdgcn_mfma_f32_16x16x32_bf16(af, CUR[grp], acc[grp & 1][grp >> 1], 0, 0, 0); \
      af = afn;

      KT_STEP(ua, ub, 0)
      KT_STEP(ub, ua, 1)
      KT_STEP(ua, ub, 2)
      KT_STEP(ub, ua, 3)
      KT_STEP(ua, ub, 4)
      KT_STEP(ub, ua, 5)
      KT_STEP(ua, ub, 6)
      KT_STEP(ub, ua, 7)
#undef KT_STEP
    }

    // gates + cell update for the 8 (ct2,row) cells this lane owns
    float hv0[4], hv1[4];
#pragma unroll
    for (int r = 0; r < 4; ++r) {
      float pi = acc[0][0][r] + bf2f(pf0[r].x) + bs0.x;
      float pv = acc[0][1][r] + bf2f(pf0[r].y) + bs0.y;
      float po = acc[0][2][r] + bf2f(pf0[r].z) + bs0.z;
      float pg = acc[0][3][r] + bf2f(pf0[r].w) + bs0.w;
      float cn = sigm(pi) * tanh_f(pg) + sigm(pv) * c0[r];
      c0[r] = cn;
      hv0[r] = sigm(po) * tanh_f(cn);
      pi = acc[1][0][r] + bf2f(pf1[r].x) + bs1.x;
      pv = acc[1][1][r] + bf2f(pf1[r].y) + bs1.y;
      po = acc[1][2][r] + bf2f(pf1[r].z) + bs1.z;
      pg = acc[1][3][r] + bf2f(pf1[r].w) + bs1.w;
      cn = sigm(pi) * tanh_f(pg) + sigm(pv) * c1[r];
      c1[r] = cn;
      hv1[r] = sigm(po) * tanh_f(cn);
    }

    if (t < TT - 1) {
      ushort_t* hw = &hl[t & 1][0][0];
#pragma unroll
      for (int r = 0; r < 4; ++r) {
        hw[(rowl + r) * 264 + jc0] = f2bf(hv0[r]);
        hw[(rowl + r) * 264 + jc1] = f2bf(hv1[r]);
      }
      __syncthreads();
    } else {
#pragma unroll
      for (int r = 0; r < 4; ++r) {
        hfin[(size_t)(b * 16 + rowl + r) * 256 + jc0] = hv0[r];
        hfin[(size_t)(b * 16 + rowl + r) * 256 + jc1] = hv1[r];
      }
    }
  }
}

// ---------- K3: out = normalize(h @ fc_w + fc_b) ----------
__global__ __launch_bounds__(256) void k3_fc(const float* __restrict__ hfin,
                                             const float* __restrict__ fcw,
                                             const float* __restrict__ fcb,
                                             float* __restrict__ out) {
  __shared__ float hrow[256];
  __shared__ float red[4];
  const int b = blockIdx.x, j = threadIdx.x;
  hrow[j] = hfin[(size_t)b * 256 + j];
  __syncthreads();
  float acc = fcb[j];
#pragma unroll 4
  for (int k = 0; k < 256; ++k) acc = fmaf(hrow[k], fcw[(size_t)k * 256 + j], acc);
  float ss = acc * acc;
#pragma unroll
  for (int o = 32; o > 0; o >>= 1) ss += __shfl_down(ss, o);
  if ((j & 63) == 0) red[j >> 6] = ss;
  __syncthreads();
  float tot = red[0] + red[1] + red[2] + red[3];
  float nrm = fmaxf(sqrtf(tot), 1e-12f);
  out[(size_t)b * 256 + j] = acc / nrm;
}

extern "C" void kernel_launch(void* const* d_in, const int* in_sizes, int n_in,
                              void* d_out, int out_size, void* d_ws, size_t ws_size,
                              hipStream_t stream) {
  const int* captions = (const int*)d_in[0];
  const float* emb = (const float*)d_in[1];
  const float *W[4], *bW[4], *U[4], *bU[4];
  for (int g = 0; g < 4; ++g) {
    W[g]  = (const float*)d_in[2 + 4 * g];
    bW[g] = (const float*)d_in[3 + 4 * g];
    U[g]  = (const float*)d_in[4 + 4 * g];
    bU[g] = (const float*)d_in[5 + 4 * g];
  }
  const float* fcw = (const float*)d_in[18];
  const float* fcb = (const float*)d_in[19];
  float* out = (float*)d_out;

  char* ws = (char*)d_ws;
  ushort_t* P    = (ushort_t*)(ws);                 // 32000*1024*2 = 65,536,000
  ushort_t* WT   = (ushort_t*)(ws + 65536000);      // 1024*256*2   = 524,288
  ushort_t* UP   = (ushort_t*)(ws + 66060288);      // 524,288
  float*    bias = (float*)   (ws + 66584576);      // 4,096
  float*    hfin = (float*)   (ws + 66588672);      // 512*256*4    = 524,288

  k_pack_w<<<1024, 256, 0, stream>>>(W[0], W[1], W[2], W[3], WT);
  k_pack_u<<<128, 256, 0, stream>>>(U[0], U[1], U[2], U[3], UP);
  k_bias<<<4, 256, 0, stream>>>(bW[0], bW[1], bW[2], bW[3],
                                bU[0], bU[1], bU[2], bU[3], bias);
  k1_gemm<<<2000, 256, 0, stream>>>(emb, WT, P);
  k_scan<<<32, 512, 0, stream>>>(P, UP, bias, captions, hfin);
  k3_fc<<<512, 256, 0, stream>>>(hfin, fcw, fcb, out);
}

// Round 4
// 444.647 us; speedup vs baseline: 2.1466x; 2.1466x over previous
//
#include <hip/hip_runtime.h>
#include <stdint.h>

typedef unsigned short ushort_t;
typedef __attribute__((ext_vector_type(8))) short bf8_t;     // 8 x bf16 (4 VGPRs)
typedef __attribute__((ext_vector_type(4))) float f4_t;      // MFMA accumulator
typedef __attribute__((ext_vector_type(4))) unsigned short us4_t;

#define TT 128

__device__ __forceinline__ ushort_t f2bf(float f) {
  uint32_t u = __builtin_bit_cast(uint32_t, f);
  u += 0x7fffu + ((u >> 16) & 1u);
  return (ushort_t)(u >> 16);
}
__device__ __forceinline__ float bf2f(ushort_t h) {
  uint32_t u = ((uint32_t)h) << 16;
  return __builtin_bit_cast(float, u);
}
// fast gates: v_rcp-based, no fp-division expansion
__device__ __forceinline__ float sigm(float x) {
  return __builtin_amdgcn_rcpf(1.f + __expf(-x));
}
__device__ __forceinline__ float tanh_f(float x) {
  // 1 - 2/(1+exp(2x)); exp overflow -> inf -> rcp -> 0 -> 1 (correct saturation)
  return 1.f - 2.f * __builtin_amdgcn_rcpf(1.f + __expf(2.f * x));
}

// ---- LLC-coherent (sc0 sc1) access helpers ----
__device__ __forceinline__ void store16_bypass(void* p, bf8_t v) {
  asm volatile("global_store_dwordx4 %0, %1, off sc0 sc1" :: "v"(p), "v"(v) : "memory");
}
__device__ __forceinline__ void store_flag_bypass(unsigned* p, unsigned v) {
  asm volatile("global_store_dword %0, %1, off sc0 sc1" :: "v"(p), "v"(v) : "memory");
}
__device__ __forceinline__ unsigned load_flag_bypass(const unsigned* p) {
  unsigned v;
  asm volatile("global_load_dword %0, %1, off sc0 sc1\n\ts_waitcnt vmcnt(0)"
               : "=v"(v) : "v"(p) : "memory");
  return v;
}
// issue 4 frag loads (no wait here; consumer does vmcnt(0)+sched_barrier)
__device__ __forceinline__ void load4x16_bypass(const void* p, bf8_t f[4]) {
  asm volatile(
      "global_load_dwordx4 %0, %4, off sc0 sc1\n\t"
      "global_load_dwordx4 %1, %4, off offset:1024 sc0 sc1\n\t"
      "global_load_dwordx4 %2, %4, off offset:2048 sc0 sc1\n\t"
      "global_load_dwordx4 %3, %4, off offset:3072 sc0 sc1"
      : "=&v"(f[0]), "=&v"(f[1]), "=&v"(f[2]), "=&v"(f[3])
      : "v"(p) : "memory");
}

// ---------- pack kernels ----------
// Gate-interleaved: physical output col n = col*4 + gate.  WT[n][k] = W_{g=n&3}[k][j=n>>2]
__global__ void k_pack_w(const float* W0, const float* W1, const float* W2, const float* W3,
                         ushort_t* __restrict__ o) {
  int idx = blockIdx.x * 256 + threadIdx.x;   // 0..262143
  int n = idx >> 8, k = idx & 255;
  int g = n & 3, j = n >> 2;
  const float* Wg = g == 0 ? W0 : g == 1 ? W1 : g == 2 ? W2 : W3;
  o[(size_t)n * 256 + k] = f2bf(Wg[k * 256 + j]);
}

// U frag pack for 2-block pairs: UPJ[((q*8+w)*8 + ktS)*4 + g][lane][e]
// ktS is LOCAL order (own k-half first): global kt = (ktS + 4*q) & 7.
// col = q*128 + w*16 + (lane&15); k = ktG*32 + (lane>>4)*8 + e; val = U_g[k][col]
__global__ void k_pack_u(const float* U0, const float* U1, const float* U2, const float* U3,
                         ushort_t* __restrict__ o) {
  int idx = blockIdx.x * 256 + threadIdx.x;   // 0..32767
  int lane = idx & 63, g = (idx >> 6) & 3, ktS = (idx >> 8) & 7,
      w = (idx >> 11) & 7, q = (idx >> 14) & 1;
  const float* Ug = g == 0 ? U0 : g == 1 ? U1 : g == 2 ? U2 : U3;
  int ktG = (ktS + 4 * q) & 7;
  int col = q * 128 + w * 16 + (lane & 15);
  int kb = ktG * 32 + (lane >> 4) * 8;
#pragma unroll
  for (int e = 0; e < 8; ++e)
    o[(size_t)idx * 8 + e] = f2bf(Ug[(size_t)(kb + e) * 256 + col]);
}

// bias2[n] (n = j*4+g) = bW_g[j] + bU_g[j]
__global__ void k_bias(const float* a0, const float* a1, const float* a2, const float* a3,
                       const float* b0, const float* b1, const float* b2, const float* b3,
                       float* __restrict__ o) {
  int n = blockIdx.x * 256 + threadIdx.x;  // 0..1023
  int g = n & 3, j = n >> 2;
  const float* pa = g == 0 ? a0 : g == 1 ? a1 : g == 2 ? a2 : a3;
  const float* pb = g == 0 ? b0 : g == 1 ? b1 : g == 2 ? b2 : b3;
  o[n] = pa[j] + pb[j];
}

// ---------- K1: P = emb @ W_all (emb f32 read + convert fused; bf16 MFMA) ----------
__global__ __launch_bounds__(256) void k1_gemm(const float* __restrict__ A,      // emb f32 [32000][256]
                                               const ushort_t* __restrict__ Bm,  // WT bf16 [1024][256]
                                               ushort_t* __restrict__ P) {       // [32000][1024]
  __shared__ ushort_t Al[128 * 32];
  __shared__ ushort_t Bl[128 * 32];
  const int tid = threadIdx.x;
  const int lane = tid & 63;
  const int w = tid >> 6;
  const int mt = blockIdx.x >> 3;
  const int nt = blockIdx.x & 7;
  const int m0 = mt * 128, n0 = nt * 128;
  const int qr = (w >> 1) * 64, qc = (w & 1) * 64;

  f4_t acc[4][4];
#pragma unroll
  for (int i = 0; i < 4; ++i)
#pragma unroll
    for (int j = 0; j < 4; ++j) acc[i][j] = f4_t{0.f, 0.f, 0.f, 0.f};

  const int r0 = tid >> 2, s0 = tid & 3;  // rows 0..63
  const int r1 = 64 + r0;                 // rows 64..127

  for (int k0 = 0; k0 < 256; k0 += 32) {
    float4 a00 = *(const float4*)(A + (size_t)(m0 + r0) * 256 + k0 + s0 * 8);
    float4 a01 = *(const float4*)(A + (size_t)(m0 + r0) * 256 + k0 + s0 * 8 + 4);
    float4 a10 = *(const float4*)(A + (size_t)(m0 + r1) * 256 + k0 + s0 * 8);
    float4 a11 = *(const float4*)(A + (size_t)(m0 + r1) * 256 + k0 + s0 * 8 + 4);
    bf8_t b0 = *(const bf8_t*)(Bm + (size_t)(n0 + r0) * 256 + k0 + s0 * 8);
    bf8_t b1 = *(const bf8_t*)(Bm + (size_t)(n0 + r1) * 256 + k0 + s0 * 8);
    bf8_t pa0, pa1;
    pa0[0] = (short)f2bf(a00.x); pa0[1] = (short)f2bf(a00.y);
    pa0[2] = (short)f2bf(a00.z); pa0[3] = (short)f2bf(a00.w);
    pa0[4] = (short)f2bf(a01.x); pa0[5] = (short)f2bf(a01.y);
    pa0[6] = (short)f2bf(a01.z); pa0[7] = (short)f2bf(a01.w);
    pa1[0] = (short)f2bf(a10.x); pa1[1] = (short)f2bf(a10.y);
    pa1[2] = (short)f2bf(a10.z); pa1[3] = (short)f2bf(a10.w);
    pa1[4] = (short)f2bf(a11.x); pa1[5] = (short)f2bf(a11.y);
    pa1[6] = (short)f2bf(a11.z); pa1[7] = (short)f2bf(a11.w);
    __syncthreads();
    *(bf8_t*)(Al + (size_t)tid * 8) = pa0;
    *(bf8_t*)(Al + (size_t)(256 + tid) * 8) = pa1;
    *(bf8_t*)(Bl + (size_t)tid * 8) = b0;
    *(bf8_t*)(Bl + (size_t)(256 + tid) * 8) = b1;
    __syncthreads();
    bf8_t af[4], bfr[4];
#pragma unroll
    for (int i = 0; i < 4; ++i) {
      af[i]  = *(const bf8_t*)(Al + (qr + i * 16 + (lane & 15)) * 32 + (lane >> 4) * 8);
      bfr[i] = *(const bf8_t*)(Bl + (qc + i * 16 + (lane & 15)) * 32 + (lane >> 4) * 8);
    }
#pragma unroll
    for (int i = 0; i < 4; ++i)
#pragma unroll
      for (int j = 0; j < 4; ++j)
        acc[i][j] = __builtin_amdgcn_mfma_f32_16x16x32_bf16(af[i], bfr[j], acc[i][j], 0, 0, 0);
  }
#pragma unroll
  for (int i = 0; i < 4; ++i)
#pragma unroll
    for (int j = 0; j < 4; ++j)
#pragma unroll
      for (int r = 0; r < 4; ++r) {
        int row = m0 + qr + i * 16 + (lane >> 4) * 4 + r;
        int col = n0 + qc + j * 16 + (lane & 15);
        P[(size_t)row * 1024 + col] = f2bf(acc[i][j][r]);
      }
}

// ---------- K2: 2-block pairs, U register-resident, 4KB h exchange via LLC ----------
// 32 pairs x 2 blocks; pair owns 16 batch rows; block q owns h cols [q*128,q*128+128)
// for all 4 gates with its 256KB U-slice in 128 VGPRs/thread. Per step: gates ->
// h-half transposed via LDS into A-frag layout -> 256x16B coalesced sc0sc1 stores ->
// per-step flag -> poll partner -> own-half MFMAs from LDS while partner frags load.
__global__ __launch_bounds__(512, 2) void k_scan(
    const ushort_t* __restrict__ P, const ushort_t* __restrict__ UPJ,
    const float* __restrict__ bias, const int* __restrict__ cap,
    float* __restrict__ hfin, char* __restrict__ pbuf, unsigned* __restrict__ flags) {
  __shared__ ushort_t hlds[2][2048];   // per parity: 4KB = [4 ktL][4 l16][16 m][8 e]
  const int blk = blockIdx.x;
  const int pair = blk >> 1, q = blk & 1;
  const int tid = threadIdx.x, lane = tid & 63, w = tid >> 6;
  const int l15 = lane & 15, l16 = lane >> 4;
  const int jc = q * 128 + w * 16 + l15;       // this lane's global h col
  const int row0 = pair * 16 + l16 * 4;        // global batch row base (4 cells)

  // U frags, local-kt order (own half = u[0..3], partner half = u[4..7])
  bf8_t u[8][4];
  {
    const ushort_t* ub = UPJ + (size_t)(q * 8 + w) * 32 * 512 + (size_t)lane * 8;
#pragma unroll
    for (int kt = 0; kt < 8; ++kt)
#pragma unroll
      for (int g = 0; g < 4; ++g)
        u[kt][g] = *(const bf8_t*)(ub + (kt * 4 + g) * 512);
  }
  const float4 bs = *(const float4*)(bias + jc * 4);

  float c[4] = {0.f, 0.f, 0.f, 0.f};
  f4_t acc[4];
#pragma unroll
  for (int g = 0; g < 4; ++g) acc[g] = f4_t{0.f, 0.f, 0.f, 0.f};

  // P quad prefetch for t=0 (plain cached loads)
  us4_t pf[4];
#pragma unroll
  for (int r = 0; r < 4; ++r) {
    int tokr = cap[(row0 + r) * TT];
    pf[r] = *(const us4_t*)(P + (size_t)tokr * 1024 + jc * 4);
  }

  // LDS write index: frag-row = wfrag, element = l15&7, row = 4*l16 + r
  const int wfrag = (w >> 1) * 4 + (w & 1) * 2 + (l15 >> 3);
  const int wbase = wfrag * 128 + l16 * 32 + (l15 & 7);

  char* pairbuf = pbuf + (size_t)pair * 16384;
  unsigned* fown = flags + (pair * 2 + q) * TT;
  const unsigned* fpar = flags + (pair * 2 + (1 - q)) * TT;

  for (int t = 0; t < TT; ++t) {
    // ---- gates + cell update (4 cells: col jc, rows row0..row0+3) ----
    float hv[4];
#pragma unroll
    for (int r = 0; r < 4; ++r) {
      float pi = acc[0][r] + bf2f(pf[r].x) + bs.x;
      float pF = acc[1][r] + bf2f(pf[r].y) + bs.y;
      float po = acc[2][r] + bf2f(pf[r].z) + bs.z;
      float pg = acc[3][r] + bf2f(pf[r].w) + bs.w;
      float ig = sigm(pi), fg = sigm(pF), og = sigm(po), gg = tanh_f(pg);
      float cn = fmaf(fg, c[r], ig * gg);
      c[r] = cn;
      hv[r] = og * tanh_f(cn);
    }
    if (t == TT - 1) {
#pragma unroll
      for (int r = 0; r < 4; ++r)
        hfin[(size_t)(row0 + r) * 256 + jc] = hv[r];
      break;
    }
    const int par = t & 1;
    // ---- h -> LDS (A-frag layout) ----
    {
      ushort_t* hb = &hlds[par][0];
#pragma unroll
      for (int r = 0; r < 4; ++r) hb[wbase + r * 8] = f2bf(hv[r]);
    }
    __syncthreads();
    // ---- LDS -> LLC exchange buffer, coalesced 16B ----
    if (tid < 256) {
      bf8_t v = *(const bf8_t*)(&hlds[par][tid * 8]);
      store16_bypass(pairbuf + par * 8192 + q * 4096 + tid * 16, v);
    }
    asm volatile("s_waitcnt vmcnt(0)" ::: "memory");   // data at LLC
    __syncthreads();
    // ---- P prefetch t+1 (after drain: keeps HBM latency off the flag path) ----
#pragma unroll
    for (int r = 0; r < 4; ++r) {
      int tokr = cap[(row0 + r) * TT + t + 1];
      pf[r] = *(const us4_t*)(P + (size_t)tokr * 1024 + jc * 4);
    }
    // ---- flag + poll partner ----
    if (tid == 0) {
      store_flag_bypass(fown + t, 1u);
      while (load_flag_bypass(fpar + t) == 0) __builtin_amdgcn_s_sleep(1);
    }
    __syncthreads();
    // ---- MFMA: acc for step t+1 ----
#pragma unroll
    for (int g = 0; g < 4; ++g) acc[g] = f4_t{0.f, 0.f, 0.f, 0.f};
    bf8_t paf[4];
    load4x16_bypass(pairbuf + par * 8192 + (1 - q) * 4096 + (l16 * 16 + l15) * 16, paf);
    // own half from LDS while partner frags are in flight
#pragma unroll
    for (int kt = 0; kt < 4; ++kt) {
      bf8_t afk = *(const bf8_t*)(&hlds[par][((kt * 4 + l16) * 16 + l15) * 8]);
#pragma unroll
      for (int g = 0; g < 4; ++g)
        acc[g] = __builtin_amdgcn_mfma_f32_16x16x32_bf16(afk, u[kt][g], acc[g], 0, 0, 0);
    }
    asm volatile("s_waitcnt vmcnt(0)" ::: "memory");
    __builtin_amdgcn_sched_barrier(0);
#pragma unroll
    for (int kt = 0; kt < 4; ++kt)
#pragma unroll
      for (int g = 0; g < 4; ++g)
        acc[g] = __builtin_amdgcn_mfma_f32_16x16x32_bf16(paf[kt], u[4 + kt][g], acc[g], 0, 0, 0);
  }
}

// ---------- K3: out = normalize(h @ fc_w + fc_b) ----------
__global__ __launch_bounds__(256) void k3_fc(const float* __restrict__ hfin,
                                             const float* __restrict__ fcw,
                                             const float* __restrict__ fcb,
                                             float* __restrict__ out) {
  __shared__ float hrow[256];
  __shared__ float red[4];
  const int b = blockIdx.x, j = threadIdx.x;
  hrow[j] = hfin[(size_t)b * 256 + j];
  __syncthreads();
  float acc = fcb[j];
#pragma unroll 4
  for (int k = 0; k < 256; ++k) acc = fmaf(hrow[k], fcw[(size_t)k * 256 + j], acc);
  float ss = acc * acc;
#pragma unroll
  for (int o = 32; o > 0; o >>= 1) ss += __shfl_down(ss, o);
  if ((j & 63) == 0) red[j >> 6] = ss;
  __syncthreads();
  float tot = red[0] + red[1] + red[2] + red[3];
  float nrm = fmaxf(sqrtf(tot), 1e-12f);
  out[(size_t)b * 256 + j] = acc / nrm;
}

extern "C" void kernel_launch(void* const* d_in, const int* in_sizes, int n_in,
                              void* d_out, int out_size, void* d_ws, size_t ws_size,
                              hipStream_t stream) {
  const int* captions = (const int*)d_in[0];
  const float* emb = (const float*)d_in[1];
  const float *W[4], *bW[4], *U[4], *bU[4];
  for (int g = 0; g < 4; ++g) {
    W[g]  = (const float*)d_in[2 + 4 * g];
    bW[g] = (const float*)d_in[3 + 4 * g];
    U[g]  = (const float*)d_in[4 + 4 * g];
    bU[g] = (const float*)d_in[5 + 4 * g];
  }
  const float* fcw = (const float*)d_in[18];
  const float* fcb = (const float*)d_in[19];
  float* out = (float*)d_out;

  char* ws = (char*)d_ws;
  ushort_t* P     = (ushort_t*)(ws);                 // 32000*1024*2 = 65,536,000
  ushort_t* WT    = (ushort_t*)(ws + 65536000);      // 524,288
  ushort_t* UPJ   = (ushort_t*)(ws + 66060288);      // 524,288
  float*    bias  = (float*)   (ws + 66584576);      // 4,096
  float*    hfin  = (float*)   (ws + 66588672);      // 524,288
  char*     pbuf  = (char*)    (ws + 67112960);      // 32*2*2*4096 = 524,288
  unsigned* flags = (unsigned*)(ws + 67637248);      // 32*2*128*4  = 32,768

  hipMemsetAsync(flags, 0, 32768, stream);
  k_pack_w<<<1024, 256, 0, stream>>>(W[0], W[1], W[2], W[3], WT);
  k_pack_u<<<128, 256, 0, stream>>>(U[0], U[1], U[2], U[3], UPJ);
  k_bias<<<4, 256, 0, stream>>>(bW[0], bW[1], bW[2], bW[3],
                                bU[0], bU[1], bU[2], bU[3], bias);
  k1_gemm<<<2000, 256, 0, stream>>>(emb, WT, P);
  k_scan<<<64, 512, 0, stream>>>(P, UPJ, bias, captions, hfin, pbuf, flags);
  k3_fc<<<512, 256, 0, stream>>>(hfin, fcw, fcb, out);
}